// Round 3
// baseline (889.854 us; speedup 1.0000x reference)
//
#include <hip/hip_runtime.h>
#include <hip/hip_bf16.h>

#define VOCAB 50257
#define NPAD  50304   // 393 * 128
#define MROWS 4096    // B*S
#define SEQ   2048
#define KDIM  1024

typedef __attribute__((ext_vector_type(4))) float f32x4;
typedef __attribute__((ext_vector_type(8))) short bf16x8;

#define AS1 __attribute__((address_space(1)))
#define AS3 __attribute__((address_space(3)))

__device__ __forceinline__ unsigned int f2bf_pair(float lo, float hi) {
  unsigned int a = __float_as_uint(lo);
  a = (a + 0x7FFFu + ((a >> 16) & 1u)) >> 16;
  unsigned int b = __float_as_uint(hi);
  b = (b + 0x7FFFu + ((b >> 16) & 1u)) >> 16;
  return a | (b << 16);
}

// one uint4 (8 bf16) per thread
__global__ void cast_hidden_k(const float* __restrict__ src, uint4* __restrict__ dst) {
  int i = blockIdx.x * 256 + threadIdx.x;
  const float4* s = ((const float4*)src) + (size_t)i * 2;
  float4 a = s[0], b = s[1];
  uint4 o;
  o.x = f2bf_pair(a.x, a.y);
  o.y = f2bf_pair(a.z, a.w);
  o.z = f2bf_pair(b.x, b.y);
  o.w = f2bf_pair(b.z, b.w);
  dst[i] = o;
}

// pads rows [VOCAB, NPAD) with zeros; 128 uint4-chunks per row of 1024
__global__ void cast_weight_k(const float* __restrict__ src, uint4* __restrict__ dst) {
  int i = blockIdx.x * 256 + threadIdx.x;
  int row = i >> 7;
  uint4 o = make_uint4(0u, 0u, 0u, 0u);
  if (row < VOCAB) {
    const float4* s = ((const float4*)src) + (size_t)i * 2;
    float4 a = s[0], b = s[1];
    o.x = f2bf_pair(a.x, a.y);
    o.y = f2bf_pair(a.z, a.w);
    o.z = f2bf_pair(b.x, b.y);
    o.w = f2bf_pair(b.z, b.w);
  }
  dst[i] = o;
}

// 128x128 tile, BK=32, 4 waves (2x2), each wave 64x64 = 4x4 frags of 16x16x32.
// C[m][v] = sum_k hidden[m,k] * W[v,k]; epilogue: softcap -> exp-sum per row + label pick.
__global__ __launch_bounds__(256) void gemm_ce_k(
    const unsigned short* __restrict__ A,   // [MROWS][KDIM] bf16
    const unsigned short* __restrict__ W,   // [NPAD][KDIM] bf16 (zero-padded)
    const int* __restrict__ labels,         // [MROWS] int32
    float* __restrict__ row_sum,            // [MROWS] pre-zeroed
    float* __restrict__ picked)             // [MROWS]
{
  __shared__ __align__(16) unsigned short Asm_[128 * 32];
  __shared__ __align__(16) unsigned short Wsm_[128 * 32];

  const int bid  = blockIdx.x;
  const int mblk = bid & 31;    // 32 row-blocks fastest: same W-panel streams all of A
  const int nblk = bid >> 5;    // 393 vocab-blocks
  const int tid  = threadIdx.x;
  const int lane = tid & 63;
  const int w    = tid >> 6;
  const int wm   = w >> 1;
  const int wn   = w & 1;

  const int arow0 = mblk * 128;
  const int wrow0 = nblk * 128;

  f32x4 acc[4][4];
  const f32x4 zero = {0.f, 0.f, 0.f, 0.f};
#pragma unroll
  for (int m = 0; m < 4; ++m)
#pragma unroll
    for (int n = 0; n < 4; ++n) acc[m][n] = zero;

  // staging: lane covers row (lane>>2), k-offset (lane&3)*8 within a 16-row chunk
  const int sa_row = lane >> 2;
  const int sa_col = (lane & 3) * 8;
  // fragment reads: row (lane&15), k-chunk (lane>>4)*8
  const int rloc = lane & 15;
  const int kloc = (lane >> 4) * 8;

  for (int kb = 0; kb < KDIM; kb += 32) {
#pragma unroll
    for (int c = 0; c < 2; ++c) {
      const int rchunk = (c * 4 + w) * 16;  // wave-uniform
      const unsigned short* ga = A + (size_t)(arow0 + rchunk + sa_row) * KDIM + kb + sa_col;
      __builtin_amdgcn_global_load_lds((const AS1 void*)ga, (AS3 void*)(Asm_ + rchunk * 32), 16, 0, 0);
      const unsigned short* gw = W + (size_t)(wrow0 + rchunk + sa_row) * KDIM + kb + sa_col;
      __builtin_amdgcn_global_load_lds((const AS1 void*)gw, (AS3 void*)(Wsm_ + rchunk * 32), 16, 0, 0);
    }
    __syncthreads();  // drains vmcnt -> LDS tile ready

    bf16x8 af[4], bf[4];
#pragma unroll
    for (int m = 0; m < 4; ++m)
      af[m] = *(const bf16x8*)(Asm_ + (wm * 64 + m * 16 + rloc) * 32 + kloc);
#pragma unroll
    for (int n = 0; n < 4; ++n)
      bf[n] = *(const bf16x8*)(Wsm_ + (wn * 64 + n * 16 + rloc) * 32 + kloc);
#pragma unroll
    for (int m = 0; m < 4; ++m)
#pragma unroll
      for (int n = 0; n < 4; ++n)
        acc[m][n] = __builtin_amdgcn_mfma_f32_16x16x32_bf16(af[m], bf[n], acc[m][n], 0, 0, 0);
    __syncthreads();
  }

  // epilogue: C[grow][v], grow = (lane>>4)*4 + r rows, v = lane&15 cols
#pragma unroll
  for (int m = 0; m < 4; ++m) {
#pragma unroll
    for (int r = 0; r < 4; ++r) {
      const int grow = arow0 + wm * 64 + m * 16 + (lane >> 4) * 4 + r;
      int lab = -1;  // sentinel: never matches v >= 0
      if ((grow & (SEQ - 1)) != (SEQ - 1)) lab = labels[grow + 1];  // shifted label
      float s = 0.f;
#pragma unroll
      for (int n = 0; n < 4; ++n) {
        const int v = wrow0 + wn * 64 + n * 16 + (lane & 15);
        const float z = acc[m][n][r];
        // softcap: 30*tanh(z/30) = 30*(1 - 2/(exp(2z/30)+1)); saturates correctly at +-30
        const float e2 = __expf(z * (2.f / 30.f));
        const float capped = 30.f * (1.f - 2.f * __builtin_amdgcn_rcpf(e2 + 1.f));
        if (v == lab) picked[grow] = capped;
        s += (v < VOCAB) ? __expf(capped) : 0.f;  // mask pad columns
      }
      // reduce across the 16 lanes holding this row's columns
      s += __shfl_xor(s, 1);
      s += __shfl_xor(s, 2);
      s += __shfl_xor(s, 4);
      s += __shfl_xor(s, 8);
      if ((lane & 15) == 0) atomicAdd(&row_sum[grow], s);
    }
  }
}

__global__ void reduce_k(const int* __restrict__ labels, const float* __restrict__ row_sum,
                         const float* __restrict__ picked, float* __restrict__ out)
{
  const int tid = threadIdx.x;
  float ce = 0.f, zl = 0.f;
  int cnt = 0;
  for (int r = tid; r < MROWS; r += 256) {
    if ((r & (SEQ - 1)) == (SEQ - 1)) continue;  // no next-token label in-batch
    const int lab = labels[r + 1];
    if (lab == -100) continue;                   // IGNORE_INDEX
    const float lz = __logf(row_sum[r]);         // logits capped at 30 -> no-max LSE is safe
    ce += lz - picked[r];
    zl += lz * lz;
    ++cnt;
  }
  __shared__ float sce[4], szl[4];
  __shared__ int scnt[4];
#pragma unroll
  for (int off = 32; off > 0; off >>= 1) {
    ce  += __shfl_down(ce, off);
    zl  += __shfl_down(zl, off);
    cnt += __shfl_down(cnt, off);
  }
  const int wv = tid >> 6;
  if ((tid & 63) == 0) { sce[wv] = ce; szl[wv] = zl; scnt[wv] = cnt; }
  __syncthreads();
  if (tid == 0) {
    float C = 0.f, Z = 0.f;
    int N = 0;
    for (int i = 0; i < 4; ++i) { C += sce[i]; Z += szl[i]; N += scnt[i]; }
    if (N < 1) N = 1;
    out[0] = C / N + 1e-4f * (Z / N);
  }
}

extern "C" void kernel_launch(void* const* d_in, const int* in_sizes, int n_in,
                              void* d_out, int out_size, void* d_ws, size_t ws_size,
                              hipStream_t stream) {
  const float* hidden = (const float*)d_in[0];
  const float* weight = (const float*)d_in[1];
  const int*   labels = (const int*)d_in[2];
  float* out = (float*)d_out;

  const size_t A_BYTES = (size_t)MROWS * KDIM * 2;        // 8 MiB
  const size_t W_BYTES = (size_t)NPAD * KDIM * 2;         // ~103 MB
  const size_t NEEDED  = A_BYTES + W_BYTES + 2 * MROWS * sizeof(float);
  if (ws_size < NEEDED) return;  // refuse to write OOB: fails validation loudly, not a crash

  char* ws = (char*)d_ws;
  unsigned short* Abf = (unsigned short*)ws;
  unsigned short* Wbf = (unsigned short*)(ws + A_BYTES);
  float* row_sum = (float*)(ws + A_BYTES + W_BYTES);
  float* picked  = row_sum + MROWS;

  hipMemsetAsync(row_sum, 0, MROWS * sizeof(float), stream);
  cast_hidden_k<<<MROWS * KDIM / 8 / 256, 256, 0, stream>>>(hidden, (uint4*)Abf);
  cast_weight_k<<<NPAD * KDIM / 8 / 256, 256, 0, stream>>>(weight, (uint4*)Wbf);
  gemm_ce_k<<<32 * 393, 256, 0, stream>>>(Abf, Wbf, labels, row_sum, picked);
  reduce_k<<<1, 256, 0, stream>>>(labels, row_sum, picked, out);
}